// Round 4
// baseline (603.583 us; speedup 1.0000x reference)
//
#include <hip/hip_runtime.h>
#include <math.h>

namespace {

typedef short short8 __attribute__((ext_vector_type(8)));
typedef float f32x16 __attribute__((ext_vector_type(16)));
typedef unsigned int u32;

constexpr int NEX = 256, LLEN = 2048, FEATS = 8192;
constexpr int PL = 512;          // 4*Dmax zeros on the left
constexpr int XSZ = 4096;

// packed bf16 split: (lo_bf16 << 16) | hi_bf16, both RNE
__device__ __forceinline__ u32 bfsplit(float x) {
  u32 b = __float_as_uint(x);
  u32 hb = (b + 0x7fffu + ((b >> 16) & 1u)) >> 16;
  float lo = x - __uint_as_float(hb << 16);
  u32 b2 = __float_as_uint(lo);
  u32 lb = (b2 + 0x7fffu + ((b2 >> 16) & 1u)) >> 16;
  return hb | (lb << 16);
}

// max3-friendly 8-way trees
__device__ __forceinline__ float max8(float a,float b,float c,float d,
                                      float e,float f,float g,float h) {
  return fmaxf(fmaxf(fmaxf(fmaxf(a,b),c), fmaxf(fmaxf(d,e),f)), fmaxf(g,h));
}
__device__ __forceinline__ float min8(float a,float b,float c,float d,
                                      float e,float f,float g,float h) {
  return fminf(fminf(fminf(fminf(a,b),c), fminf(fminf(d,e),f)), fminf(g,h));
}

#define MFMA __builtin_amdgcn_mfma_f32_32x32x16_bf16

template<int D, int DI>
__device__ __forceinline__ void body(
    const float* __restrict__ X, const float* __restrict__ W,
    float* __restrict__ out, u32* xhl, float* scratch, float* fin)
{
  const int n = blockIdx.x, diff = blockIdx.y, tid = threadIdx.x;
  const int lane = tid & 63, wave = tid >> 6;
  const int col = lane & 31, hi = lane >> 5;

  // ---- stage padded input as packed bf16 hi/lo (diff on the fly) ----
  const float* xr = X + n * LLEN;
  for (int i = tid; i < XSZ; i += 256) {
    float x = 0.f;
    if (diff) { if (i >= PL && i < PL + LLEN - 1) x = xr[i - PL + 1] - xr[i - PL]; }
    else      { if (i >= PL && i < PL + LLEN)     x = xr[i - PL]; }
    xhl[i] = bfsplit(x);
  }
  __syncthreads();

  const float* wall = W + (DI * 2 + diff) * (256 * 9);

  // Permuted A-row -> kernel map so each lane owns two complete 8-k groups:
  // row r holds kernel g*8+k with g = 2*(r>>4) + ((r>>2)&1), k = (r&3) + 4*((r>>3)&1).
  // Then c[0..7] = k 0..7 of group (hi + 2*0-tile), c[8..15] = group (hi+2).
  const int g_of_r = ((col >> 4) << 1) | ((col >> 2) & 1);
  const int k_of_r = (col & 3) | (((col >> 3) & 1) << 2);
  const int kloc = g_of_r * 8 + k_of_r;

  // A fragments for both 32-kern tiles of this wave (kt2 = 0,1)
  short8 ah0, al0, ah1, al1;
  {
    const float* w0 = wall + (wave * 64 + kloc) * 9;
    const float* w1 = w0 + 32 * 9;
    #pragma unroll
    for (int e = 0; e < 8; ++e) {
      int j = hi * 8 + e;
      float v0 = (j < 9) ? w0[j] : 0.f;
      float v1 = (j < 9) ? w1[j] : 0.f;
      u32 p0 = bfsplit(v0), p1 = bfsplit(v1);
      ah0[e] = (short)(p0 & 0xffffu); al0[e] = (short)(p0 >> 16);
      ah1[e] = (short)(p1 & 0xffffu); al1[e] = (short)(p1 >> 16);
    }
  }

  float accMa[16], accMb[16];
  int   accNa[16], accNb[16];
  #pragma unroll
  for (int i = 0; i < 16; ++i) {
    accMa[i] = 0.f; accMb[i] = 0.f; accNa[i] = 0; accNb[i] = 0;
  }

  #pragma unroll 2
  for (int tt = 0; tt < 64; ++tt) {
    // B fragment: B[j=8*hi+e][col] = x[tt*32 + col + (j-4)*D]
    const int ebase = PL + tt * 32 + col + (hi * 8 - 4) * D;
    u32 uu[8];
    #pragma unroll
    for (int e = 0; e < 8; ++e) uu[e] = xhl[ebase + e * D];
    union { short8 s; u32 u[4]; } bh, bl;
    #pragma unroll
    for (int p = 0; p < 4; ++p) {
      bh.u[p] = __builtin_amdgcn_perm(uu[2*p+1], uu[2*p], 0x05040100u);
      bl.u[p] = __builtin_amdgcn_perm(uu[2*p+1], uu[2*p], 0x07060302u);
    }

    {   // ---- kern tile kt2 = 0 ----
      f32x16 c = {};
      c = MFMA(al0, bh.s, c, 0, 0, 0);
      c = MFMA(ah0, bl.s, c, 0, 0, 0);
      c = MFMA(ah0, bh.s, c, 0, 0, 0);
      float zx0 = max8(c[0],c[1],c[2],c[3],c[4],c[5],c[6],c[7]);
      float zn0 = min8(c[0],c[1],c[2],c[3],c[4],c[5],c[6],c[7]);
      float zx1 = max8(c[8],c[9],c[10],c[11],c[12],c[13],c[14],c[15]);
      float zn1 = min8(c[8],c[9],c[10],c[11],c[12],c[13],c[14],c[15]);
      #pragma unroll
      for (int i = 0; i < 8; ++i) {
        accMa[i] += (c[i] == zx0) ? c[i] : 0.f;
        accNa[i] += (c[i] == zn0) ? 1 : 0;
      }
      #pragma unroll
      for (int i = 8; i < 16; ++i) {
        accMa[i] += (c[i] == zx1) ? c[i] : 0.f;
        accNa[i] += (c[i] == zn1) ? 1 : 0;
      }
    }
    {   // ---- kern tile kt2 = 1 ----
      f32x16 c = {};
      c = MFMA(al1, bh.s, c, 0, 0, 0);
      c = MFMA(ah1, bl.s, c, 0, 0, 0);
      c = MFMA(ah1, bh.s, c, 0, 0, 0);
      float zx0 = max8(c[0],c[1],c[2],c[3],c[4],c[5],c[6],c[7]);
      float zn0 = min8(c[0],c[1],c[2],c[3],c[4],c[5],c[6],c[7]);
      float zx1 = max8(c[8],c[9],c[10],c[11],c[12],c[13],c[14],c[15]);
      float zn1 = min8(c[8],c[9],c[10],c[11],c[12],c[13],c[14],c[15]);
      #pragma unroll
      for (int i = 0; i < 8; ++i) {
        accMb[i] += (c[i] == zx0) ? c[i] : 0.f;
        accNb[i] += (c[i] == zn0) ? 1 : 0;
      }
      #pragma unroll
      for (int i = 8; i < 16; ++i) {
        accMb[i] += (c[i] == zx1) ? c[i] : 0.f;
        accNb[i] += (c[i] == zn1) ? 1 : 0;
      }
    }
  }

  // ---- flush: per-wave XOR-swizzled [32][32] transpose, 4 rounds ----
  // acc index i of lane (col,hi) is local kern s = 8*hi + 16*(i>>3) + (i&7).
  float* sw = scratch + wave * 1024;
  float sM0 = 0.f, sN0 = 0.f, sM1 = 0.f, sN1 = 0.f;

  #pragma unroll
  for (int i = 0; i < 16; ++i) {
    int s = 8 * hi + 16 * (i >> 3) + (i & 7);
    sw[s * 32 + (col ^ s)] = accMa[i];
  }
  if (lane < 32) {
    #pragma unroll
    for (int j = 0; j < 32; ++j) sM0 += sw[lane * 32 + (j ^ lane)];
  }
  #pragma unroll
  for (int i = 0; i < 16; ++i) {
    int s = 8 * hi + 16 * (i >> 3) + (i & 7);
    sw[s * 32 + (col ^ s)] = (float)accNa[i];
  }
  if (lane < 32) {
    #pragma unroll
    for (int j = 0; j < 32; ++j) sN0 += sw[lane * 32 + (j ^ lane)];
  }
  #pragma unroll
  for (int i = 0; i < 16; ++i) {
    int s = 8 * hi + 16 * (i >> 3) + (i & 7);
    sw[s * 32 + (col ^ s)] = accMb[i];
  }
  if (lane < 32) {
    #pragma unroll
    for (int j = 0; j < 32; ++j) sM1 += sw[lane * 32 + (j ^ lane)];
  }
  #pragma unroll
  for (int i = 0; i < 16; ++i) {
    int s = 8 * hi + 16 * (i >> 3) + (i & 7);
    sw[s * 32 + (col ^ s)] = (float)accNb[i];
  }
  if (lane < 32) {
    #pragma unroll
    for (int j = 0; j < 32; ++j) sN1 += sw[lane * 32 + (j ^ lane)];
    *(float2*)(fin + ((wave * 32 + lane) * 2 + 0) * 2) = make_float2(sM0, sN0);
    *(float2*)(fin + ((wave * 32 + lane) * 2 + 1) * 2) = make_float2(sM1, sN1);
  }
  __syncthreads();

  // ---- final: tid = kern (single owner, no cross-wave sum) ----
  const int w2 = tid >> 6, kt2f = (tid >> 5) & 1, r = tid & 31;
  float2 mn2 = *(const float2*)(fin + ((w2 * 32 + r) * 2 + kt2f) * 2);
  float M = mn2.x, N = mn2.y;

  if (diff) {
    // remove the spurious t=2047 column (diff branch has 2047 timesteps)
    const float* wrow = wall + tid * 9;
    float z = 0.f;
    #pragma unroll
    for (int j = 0; j < 9; ++j) {
      u32 u = xhl[PL + (LLEN - 1) + (j - 4) * D];
      float xh = __uint_as_float((u & 0xffffu) << 16);
      float xl = __uint_as_float((u >> 16) << 16);
      u32 wp = bfsplit(wrow[j]);
      float wh = __uint_as_float((wp & 0xffffu) << 16);
      float wl = __uint_as_float((wp >> 16) << 16);
      z += wh * xh + wh * xl + wl * xh;
    }
    float* zrow = scratch;
    zrow[tid] = z;
    __syncthreads();
    const int h8 = tid & ~7;
    float zxv = zrow[h8], znv = zrow[h8];
    #pragma unroll
    for (int j = 1; j < 8; ++j) {
      zxv = fmaxf(zxv, zrow[h8 + j]);
      znv = fminf(znv, zrow[h8 + j]);
    }
    M -= (z == zxv) ? z : 0.f;
    N -= (z == znv) ? 1.f : 0.f;
  }

  const int base = n * FEATS + (DI * 4 + diff * 2) * 256 + tid;
  out[base]       = M > 0.f ? sqrtf(M) : 0.f;    // count_max
  out[base + 256] = N > 0.f ? sqrtf(N) : 0.f;    // count_min
}

__global__ __launch_bounds__(256, 4) void hydra_kernel(
    const float* __restrict__ X, const float* __restrict__ W,
    float* __restrict__ out)
{
  __shared__ u32   xhl[XSZ];        // 16 KB packed bf16 hi|lo
  __shared__ float scratch[4096];   // 16 KB: 4 waves x [32][32]
  __shared__ float fin[512];        // 2 KB: [4][32][2]{M,N}
  switch (blockIdx.z) {
    case 0: body<1,   0>(X, W, out, xhl, scratch, fin); break;
    case 1: body<2,   1>(X, W, out, xhl, scratch, fin); break;
    case 2: body<4,   2>(X, W, out, xhl, scratch, fin); break;
    case 3: body<8,   3>(X, W, out, xhl, scratch, fin); break;
    case 4: body<16,  4>(X, W, out, xhl, scratch, fin); break;
    case 5: body<32,  5>(X, W, out, xhl, scratch, fin); break;
    case 6: body<64,  6>(X, W, out, xhl, scratch, fin); break;
    case 7: body<128, 7>(X, W, out, xhl, scratch, fin); break;
  }
}

} // namespace

extern "C" void kernel_launch(void* const* d_in, const int* in_sizes, int n_in,
                              void* d_out, int out_size, void* d_ws, size_t ws_size,
                              hipStream_t stream) {
  const float* X = (const float*)d_in[0];
  const float* W = (const float*)d_in[1];
  float* out = (float*)d_out;
  dim3 grid(NEX, 2, 8);
  hipLaunchKernelGGL(hydra_kernel, grid, dim3(256), 0, stream, X, W, out);
}

// Round 5
// 455.458 us; speedup vs baseline: 1.3252x; 1.3252x over previous
//
#include <hip/hip_runtime.h>
#include <math.h>

namespace {

typedef short short8 __attribute__((ext_vector_type(8)));
typedef float f32x16 __attribute__((ext_vector_type(16)));
typedef unsigned int u32;

constexpr int NEX = 256, LLEN = 2048, FEATS = 8192;
constexpr int PL = 512;          // 4*Dmax zeros on the left
constexpr int XSZ = 4096;

// packed bf16 split: (lo_bf16 << 16) | hi_bf16, both RNE
__device__ __forceinline__ u32 bfsplit(float x) {
  u32 b = __float_as_uint(x);
  u32 hb = (b + 0x7fffu + ((b >> 16) & 1u)) >> 16;
  float lo = x - __uint_as_float(hb << 16);
  u32 b2 = __float_as_uint(lo);
  u32 lb = (b2 + 0x7fffu + ((b2 >> 16) & 1u)) >> 16;
  return hb | (lb << 16);
}

// 8-way trees shaped for v_max3/v_min3 fusion
__device__ __forceinline__ float max8(const f32x16& c, int o) {
  return fmaxf(fmaxf(fmaxf(c[o+0], c[o+1]), c[o+2]),
               fmaxf(fmaxf(fmaxf(c[o+3], c[o+4]), c[o+5]),
                     fmaxf(c[o+6], c[o+7])));
}
__device__ __forceinline__ float min8(const f32x16& c, int o) {
  return fminf(fminf(fminf(c[o+0], c[o+1]), c[o+2]),
               fminf(fminf(fminf(c[o+3], c[o+4]), c[o+5]),
                     fminf(c[o+6], c[o+7])));
}

#define MFMA __builtin_amdgcn_mfma_f32_32x32x16_bf16

template<int D, int DI>
__device__ __forceinline__ void body(
    const float* __restrict__ X, const float* __restrict__ W,
    float* __restrict__ out, u32* xhl, float* scratch, float* fin)
{
  const int n = blockIdx.x, diff = blockIdx.y, tid = threadIdx.x;
  const int lane = tid & 63, wave = tid >> 6;
  const int col = lane & 31, hi = lane >> 5;

  // ---- stage padded input as packed bf16 hi/lo (diff on the fly) ----
  const float* xr = X + n * LLEN;
  for (int i = tid; i < XSZ; i += 256) {
    float x = 0.f;
    if (diff) { if (i >= PL && i < PL + LLEN - 1) x = xr[i - PL + 1] - xr[i - PL]; }
    else      { if (i >= PL && i < PL + LLEN)     x = xr[i - PL]; }
    xhl[i] = bfsplit(x);
  }
  __syncthreads();

  const float* wall = W + (DI * 2 + diff) * (256 * 9);

  // Permuted A-row -> kernel map so each lane owns two complete 8-k groups:
  // row r holds kernel g*8+k, g = 2*(r>>4)+((r>>2)&1), k = (r&3)+4*((r>>3)&1).
  // Then c[0..7] = all 8 k of group (hi + 2*0), c[8..15] = group (hi + 2).
  const int g_of_r = ((col >> 4) << 1) | ((col >> 2) & 1);
  const int k_of_r = (col & 3) | (((col >> 3) & 1) << 2);
  const int kloc = g_of_r * 8 + k_of_r;

  float* sw = scratch + wave * 1024;   // per-wave [32][32] XOR-swizzled

  for (int kt2 = 0; kt2 < 2; ++kt2) {
    // A fragments for this 32-kern tile (taps padded 9->16 with zeros)
    short8 ah, al;
    {
      const float* wrow = wall + (wave * 64 + kt2 * 32 + kloc) * 9;
      #pragma unroll
      for (int e = 0; e < 8; ++e) {
        int j = hi * 8 + e;
        float wv = (j < 9) ? wrow[j] : 0.f;
        u32 p = bfsplit(wv);
        ah[e] = (short)(p & 0xffffu);
        al[e] = (short)(p >> 16);
      }
    }

    float accM[16];
    int   accN[16];
    #pragma unroll
    for (int i = 0; i < 16; ++i) { accM[i] = 0.f; accN[i] = 0; }

    #pragma unroll 2
    for (int tt = 0; tt < 64; ++tt) {
      // B fragment: B[j=8*hi+e][col] = x[tt*32 + col + (j-4)*D]
      const int ebase = PL + tt * 32 + col + (hi * 8 - 4) * D;
      u32 uu[8];
      #pragma unroll
      for (int e = 0; e < 8; ++e) uu[e] = xhl[ebase + e * D];
      union { short8 s; u32 u[4]; } bh, bl;
      #pragma unroll
      for (int p = 0; p < 4; ++p) {
        bh.u[p] = __builtin_amdgcn_perm(uu[2*p+1], uu[2*p], 0x05040100u);
        bl.u[p] = __builtin_amdgcn_perm(uu[2*p+1], uu[2*p], 0x07060302u);
      }

      f32x16 c = {};
      // (wh+wl)(xh+xl) ~= wl*xh + wh*xl + wh*xh (lo*lo dropped)
      c = MFMA(al, bh.s, c, 0, 0, 0);
      c = MFMA(ah, bl.s, c, 0, 0, 0);
      c = MFMA(ah, bh.s, c, 0, 0, 0);

      const float zx0 = max8(c, 0), zn0 = min8(c, 0);
      const float zx1 = max8(c, 8), zn1 = min8(c, 8);
      #pragma unroll
      for (int i = 0; i < 8; ++i) {
        accM[i] += (c[i] == zx0) ? c[i] : 0.f;
        accN[i] += (c[i] == zn0) ? 1 : 0;
      }
      #pragma unroll
      for (int i = 8; i < 16; ++i) {
        accM[i] += (c[i] == zx1) ? c[i] : 0.f;
        accN[i] += (c[i] == zn1) ? 1 : 0;
      }
    }

    // ---- flush: wave-private XOR-swizzled transpose (no atomics/barrier) ----
    // acc index i of lane (col,hi) is local kern s = 8*hi + 16*(i>>3) + (i&7).
    float sM = 0.f, sN = 0.f;
    #pragma unroll
    for (int i = 0; i < 16; ++i) {
      int s = 8 * hi + 16 * (i >> 3) + (i & 7);
      sw[s * 32 + (col ^ s)] = accM[i];
    }
    if (lane < 32) {
      #pragma unroll
      for (int j = 0; j < 32; ++j) sM += sw[lane * 32 + (j ^ lane)];
    }
    #pragma unroll
    for (int i = 0; i < 16; ++i) {
      int s = 8 * hi + 16 * (i >> 3) + (i & 7);
      sw[s * 32 + (col ^ s)] = (float)accN[i];
    }
    if (lane < 32) {
      #pragma unroll
      for (int j = 0; j < 32; ++j) sN += sw[lane * 32 + (j ^ lane)];
      *(float2*)(fin + ((wave * 32 + lane) * 2 + kt2) * 2) = make_float2(sM, sN);
    }
  }
  __syncthreads();

  // ---- final: tid = kern (single owner, no cross-wave sum) ----
  const int w2 = tid >> 6, kt2f = (tid >> 5) & 1, r = tid & 31;
  float2 mn2 = *(const float2*)(fin + ((w2 * 32 + r) * 2 + kt2f) * 2);
  float M = mn2.x, N = mn2.y;

  if (diff) {
    // remove the spurious t=2047 column (diff branch has 2047 timesteps)
    const float* wrow = wall + tid * 9;
    float z = 0.f;
    #pragma unroll
    for (int j = 0; j < 9; ++j) {
      u32 u = xhl[PL + (LLEN - 1) + (j - 4) * D];
      float xh = __uint_as_float((u & 0xffffu) << 16);
      float xl = __uint_as_float((u >> 16) << 16);
      u32 wp = bfsplit(wrow[j]);
      float wh = __uint_as_float((wp & 0xffffu) << 16);
      float wl = __uint_as_float((wp >> 16) << 16);
      z += wh * xh + wh * xl + wl * xh;
    }
    float* zrow = scratch;
    zrow[tid] = z;
    __syncthreads();
    const int h8 = tid & ~7;
    float zxv = zrow[h8], znv = zrow[h8];
    #pragma unroll
    for (int j = 1; j < 8; ++j) {
      zxv = fmaxf(zxv, zrow[h8 + j]);
      znv = fminf(znv, zrow[h8 + j]);
    }
    M -= (z == zxv) ? z : 0.f;
    N -= (z == znv) ? 1.f : 0.f;
  }

  const int base = n * FEATS + (DI * 4 + diff * 2) * 256 + tid;
  out[base]       = M > 0.f ? sqrtf(M) : 0.f;    // count_max
  out[base + 256] = N > 0.f ? sqrtf(N) : 0.f;    // count_min
}

__global__ __launch_bounds__(256, 4) void hydra_kernel(
    const float* __restrict__ X, const float* __restrict__ W,
    float* __restrict__ out)
{
  __shared__ u32   xhl[XSZ];        // 16 KB packed bf16 hi|lo
  __shared__ float scratch[4096];   // 16 KB: 4 waves x [32][32]
  __shared__ float fin[512];        // 2 KB: [4][32][2]{M,N}
  switch (blockIdx.z) {
    case 0: body<1,   0>(X, W, out, xhl, scratch, fin); break;
    case 1: body<2,   1>(X, W, out, xhl, scratch, fin); break;
    case 2: body<4,   2>(X, W, out, xhl, scratch, fin); break;
    case 3: body<8,   3>(X, W, out, xhl, scratch, fin); break;
    case 4: body<16,  4>(X, W, out, xhl, scratch, fin); break;
    case 5: body<32,  5>(X, W, out, xhl, scratch, fin); break;
    case 6: body<64,  6>(X, W, out, xhl, scratch, fin); break;
    case 7: body<128, 7>(X, W, out, xhl, scratch, fin); break;
  }
}

} // namespace

extern "C" void kernel_launch(void* const* d_in, const int* in_sizes, int n_in,
                              void* d_out, int out_size, void* d_ws, size_t ws_size,
                              hipStream_t stream) {
  const float* X = (const float*)d_in[0];
  const float* W = (const float*)d_in[1];
  float* out = (float*)d_out;
  dim3 grid(NEX, 2, 8);
  hipLaunchKernelGGL(hydra_kernel, grid, dim3(256), 0, stream, X, W, out);
}